// Round 1
// baseline (322.243 us; speedup 1.0000x reference)
//
#include <hip/hip_runtime.h>
#include <cstdint>
#include <cstddef>

typedef unsigned short u16;
typedef __bf16 bf16x8 __attribute__((ext_vector_type(8)));
typedef float  f32x4  __attribute__((ext_vector_type(4)));

#define DEV __device__ __forceinline__

#define B_  2
#define S_  2048
#define DM  1024
#define H_  16
#define DK  64
#define M_  (B_ * S_)   // 4096

// ---------------- workspace layout (bytes) ----------------
constexpr size_t OFF_QBF  = 0;                                 // Q proj out, bf16 [M][DM]
constexpr size_t OFF_KBF  = OFF_QBF  + (size_t)M_ * DM * 2;    // K, bf16 [B][S][DK]
constexpr size_t OFF_VBF  = OFF_KBF  + (size_t)M_ * DK * 2;    // V, bf16 [B][S][DK]
constexpr size_t OFF_VT   = OFF_VBF  + (size_t)M_ * DK * 2;    // V^T, bf16 [B][DK][S]
constexpr size_t OFF_AOBF = OFF_VT   + (size_t)M_ * DK * 2;    // attn out, bf16 [M][DM]
constexpr size_t OFF_WQT  = OFF_AOBF + (size_t)M_ * DM * 2;    // Wq^T bf16 [N][K]
constexpr size_t OFF_WOT  = OFF_WQT  + (size_t)DM * DM * 2;    // Wo^T bf16 [N][K]
constexpr size_t OFF_XQBF = OFF_WOT  + (size_t)DM * DM * 2;    // inputs_q bf16 [M][DM]

// ---------------- helpers ----------------
DEV u16 f2bf(float f) {                 // RNE f32 -> bf16
  unsigned u = __float_as_uint(f);
  u += 0x7fffu + ((u >> 16) & 1u);
  return (u16)(u >> 16);
}

DEV void gload_lds16(const void* g, void* l) {
  __builtin_amdgcn_global_load_lds(
      (const __attribute__((address_space(1))) unsigned int*)g,
      (__attribute__((address_space(3))) unsigned int*)l, 16, 0, 0);
}

// ---------------- cast f32 -> bf16, 8 elems/thread ----------------
__global__ __launch_bounds__(256) void cast_bf16_kernel(
    const float* __restrict__ in, u16* __restrict__ out, int n8) {
  const int stride = gridDim.x * blockDim.x;
  for (int i = blockIdx.x * blockDim.x + threadIdx.x; i < n8; i += stride) {
    float4 a = ((const float4*)in)[2 * i];
    float4 b = ((const float4*)in)[2 * i + 1];
    uint4 o;
    o.x = (unsigned)f2bf(a.x) | ((unsigned)f2bf(a.y) << 16);
    o.y = (unsigned)f2bf(a.z) | ((unsigned)f2bf(a.w) << 16);
    o.z = (unsigned)f2bf(b.x) | ((unsigned)f2bf(b.y) << 16);
    o.w = (unsigned)f2bf(b.z) | ((unsigned)f2bf(b.w) << 16);
    ((uint4*)out)[i] = o;
  }
}

// ---------------- transpose + cast W[R][C] f32 -> WT[C][R] bf16 ----------------
__global__ void transpose_cast_kernel(const float* __restrict__ W,
                                      u16* __restrict__ WT, int R, int C) {
  __shared__ u16 tile[32][33];
  const int c0 = blockIdx.x * 32, r0 = blockIdx.y * 32;
  for (int i = threadIdx.y; i < 32; i += 8)
    tile[i][threadIdx.x] = f2bf(W[(size_t)(r0 + i) * C + c0 + threadIdx.x]);
  __syncthreads();
  for (int i = threadIdx.y; i < 32; i += 8)
    WT[(size_t)(c0 + i) * R + r0 + threadIdx.x] = tile[threadIdx.x][i];
}

// ---------------- transpose V bf16 [b][S][DK] -> [b][DK][S] ----------------
__global__ void transpose_v_kernel(const u16* __restrict__ V, u16* __restrict__ VT) {
  __shared__ u16 tile[32][33];
  const int b = blockIdx.z;
  const u16* Vb = V + (size_t)b * S_ * DK;
  u16* Tb = VT + (size_t)b * DK * S_;
  const int c0 = blockIdx.x * 32, r0 = blockIdx.y * 32;
  for (int i = threadIdx.y; i < 32; i += 8)
    tile[i][threadIdx.x] = Vb[(size_t)(r0 + i) * DK + c0 + threadIdx.x];
  __syncthreads();
  for (int i = threadIdx.y; i < 32; i += 8)
    Tb[(size_t)(c0 + i) * S_ + r0 + threadIdx.x] = tile[threadIdx.x][i];
}

// ---------------- K/V projection: out[m][n] = X[m][:]·W[:][n] + b[n], f32, bf16 out ----------------
__global__ __launch_bounds__(256) void kv_proj_kernel(
    const float* __restrict__ X, const float* __restrict__ W,
    const float* __restrict__ bias, u16* __restrict__ out) {
  const int wave = threadIdx.x >> 6, lane = threadIdx.x & 63;
  const int m = blockIdx.x * 4 + wave;
  const float* xr = X + (size_t)m * DM;
  float acc = 0.f;
  for (int k = 0; k < DM; k += 4) {
    float4 x = *(const float4*)(xr + k);   // wave-uniform broadcast
    acc += x.x * W[(k + 0) * DK + lane];   // coalesced 256B row reads
    acc += x.y * W[(k + 1) * DK + lane];
    acc += x.z * W[(k + 2) * DK + lane];
    acc += x.w * W[(k + 3) * DK + lane];
  }
  out[(size_t)m * DK + lane] = f2bf(acc + bias[lane]);
}

// ---------------- m97-style 128x128 bf16 GEMM: C = A[M][K] * BT[N][K]^T + bias ----------------
template <int OUT_F32>
__global__ __launch_bounds__(256) void gemm_bf16_kernel(
    const u16* __restrict__ A, const u16* __restrict__ BT,
    const float* __restrict__ bias, void* __restrict__ Cout,
    int M, int N, int K) {
  __shared__ __align__(16) u16 At[128 * 32];
  __shared__ __align__(16) u16 Bt[128 * 32];
  const int tid = threadIdx.x, wave = tid >> 6, lane = tid & 63;
  const int bm = blockIdx.x, bn = blockIdx.y;
  const int wm = wave >> 1, wn = wave & 1;
  const int g = lane >> 4, c = lane & 15;
  f32x4 acc[4][4] = {};

  for (int k0 = 0; k0 < K; k0 += 32) {
    __syncthreads();
#pragma unroll
    for (int j = 0; j < 2; ++j) {
      int ls = (j * 4 + wave) * 64 + lane;   // 0..511 16B slots
      int row = ls >> 2, kc = (ls & 3) * 8;
      gload_lds16(A  + (size_t)(bm * 128 + row) * K + k0 + kc,
                  (char*)At + (size_t)(j * 4 + wave) * 1024);
      gload_lds16(BT + (size_t)(bn * 128 + row) * K + k0 + kc,
                  (char*)Bt + (size_t)(j * 4 + wave) * 1024);
    }
    asm volatile("s_waitcnt vmcnt(0)" ::: "memory");
    __syncthreads();

    bf16x8 af[4], bfr[4];
#pragma unroll
    for (int mf = 0; mf < 4; ++mf)
      af[mf] = *(const bf16x8*)(At + (wm * 64 + mf * 16 + c) * 32 + g * 8);
#pragma unroll
    for (int nf = 0; nf < 4; ++nf)
      bfr[nf] = *(const bf16x8*)(Bt + (wn * 64 + nf * 16 + c) * 32 + g * 8);
#pragma unroll
    for (int mf = 0; mf < 4; ++mf)
#pragma unroll
      for (int nf = 0; nf < 4; ++nf)
        acc[mf][nf] = __builtin_amdgcn_mfma_f32_16x16x32_bf16(
            af[mf], bfr[nf], acc[mf][nf], 0, 0, 0);
  }

  const int colb = bn * 128 + wn * 64 + c;
  const int rowb = bm * 128 + wm * 64 + g * 4;
#pragma unroll
  for (int nf = 0; nf < 4; ++nf) {
    float bs = bias[colb + nf * 16];
#pragma unroll
    for (int mf = 0; mf < 4; ++mf) {
#pragma unroll
      for (int r = 0; r < 4; ++r) {
        size_t idx = (size_t)(rowb + mf * 16 + r) * N + colb + nf * 16;
        float v = acc[mf][nf][r] + bs;
        if (OUT_F32) ((float*)Cout)[idx] = v;
        else         ((u16*)Cout)[idx]   = f2bf(v);
      }
    }
  }
}

// ---------------- causal MQA flash attention ----------------
// grid (S/64, H, B); block 256 = 4 waves, each wave 16 q rows; KV tile 64.
__global__ __launch_bounds__(256) void attn_kernel(
    const u16* __restrict__ Q,   // [B*S][DM] bf16 (head h at col h*64)
    const u16* __restrict__ K,   // [B][S][DK] bf16
    const u16* __restrict__ Vt,  // [B][DK][S] bf16
    u16* __restrict__ O) {       // [B*S][DM] bf16
  __shared__ __align__(16) u16 Ktile[64 * 64];       // [kv][dk], 16B-slot XOR swizzled
  __shared__ __align__(16) u16 Vtile[64 * 64];       // [dv][kv], swizzled
  __shared__ __align__(16) u16 Plds[4][16 * 72];     // per-wave P, padded stride 72

  const int qb = blockIdx.x, h = blockIdx.y, b = blockIdx.z;
  const int tid = threadIdx.x, wave = tid >> 6, lane = tid & 63;
  const int g = lane >> 4, c = lane & 15;

  // Q fragments for this wave's 16 rows (A-layout: row=c, k=g*8+i)
  const u16* Qp = Q + ((size_t)(b * S_ + qb * 64 + wave * 16 + c) * DM) + h * DK;
  const bf16x8 qf0 = *(const bf16x8*)(Qp + g * 8);
  const bf16x8 qf1 = *(const bf16x8*)(Qp + 32 + g * 8);

  f32x4 acc[4] = {};
  float mrow[4] = {-1e30f, -1e30f, -1e30f, -1e30f};
  float lrow[4] = {0.f, 0.f, 0.f, 0.f};

  const u16* Kp = K + (size_t)b * S_ * DK;
  const u16* Vp = Vt + (size_t)b * DK * S_;
  u16* pw = &Plds[wave][0];

  for (int t = 0; t <= qb; ++t) {
    const int kv0 = t * 64;
    __syncthreads();
    // stage K tile [64][64] and V^T tile [64][64]; swizzle the GLOBAL source
    // (LDS dest of global_load_lds is linear: wave base + lane*16)
#pragma unroll
    for (int j = 0; j < 2; ++j) {
      int ls = (j * 4 + wave) * 64 + lane;   // 0..511
      int row = ls >> 3;
      int ssl = (ls & 7) ^ (row & 7);
      gload_lds16(Kp + (size_t)(kv0 + row) * DK + ssl * 8,
                  (char*)Ktile + (size_t)(j * 4 + wave) * 1024);
      gload_lds16(Vp + (size_t)row * S_ + kv0 + ssl * 8,
                  (char*)Vtile + (size_t)(j * 4 + wave) * 1024);
    }
    asm volatile("s_waitcnt vmcnt(0)" ::: "memory");
    __syncthreads();

    // S = Q · K^T  (D: row q = g*4+r, col kv = c within each 16-wide nf tile)
    f32x4 sf[4] = {};
#pragma unroll
    for (int ks = 0; ks < 2; ++ks) {
      bf16x8 qk = ks ? qf1 : qf0;
#pragma unroll
      for (int nf = 0; nf < 4; ++nf) {
        int Rr = nf * 16 + c;
        int kblk = ks * 4 + g;
        bf16x8 kf = *(const bf16x8*)(Ktile + Rr * 64 + ((kblk ^ (Rr & 7)) * 8));
        sf[nf] = __builtin_amdgcn_mfma_f32_16x16x32_bf16(qk, kf, sf[nf], 0, 0, 0);
      }
    }

    // scale + causal mask (only the diagonal tile needs masking)
    float p[4][4];
    float tmax[4] = {-1e30f, -1e30f, -1e30f, -1e30f};
    const bool diag = (t == qb);
#pragma unroll
    for (int nf = 0; nf < 4; ++nf) {
#pragma unroll
      for (int r = 0; r < 4; ++r) {
        float v = sf[nf][r] * 0.125f;
        if (diag) {
          int kv = nf * 16 + c;          // within-tile
          int q  = wave * 16 + g * 4 + r;
          if (kv > q) v = -1e30f;
        }
        p[nf][r] = v;
        tmax[r] = fmaxf(tmax[r], v);
      }
    }

    // online softmax per row (state replicated across the 16-lane group)
#pragma unroll
    for (int r = 0; r < 4; ++r) {
      float tm = tmax[r];
      tm = fmaxf(tm, __shfl_xor(tm, 1));
      tm = fmaxf(tm, __shfl_xor(tm, 2));
      tm = fmaxf(tm, __shfl_xor(tm, 4));
      tm = fmaxf(tm, __shfl_xor(tm, 8));
      float nm = fmaxf(mrow[r], tm);
      float cr = __expf(mrow[r] - nm);
      mrow[r] = nm;
      lrow[r] *= cr;
#pragma unroll
      for (int nf = 0; nf < 4; ++nf) acc[nf][r] *= cr;
      float rs = 0.f;
#pragma unroll
      for (int nf = 0; nf < 4; ++nf) {
        float e = __expf(p[nf][r] - nm);
        p[nf][r] = e;
        rs += e;
      }
      rs += __shfl_xor(rs, 1);
      rs += __shfl_xor(rs, 2);
      rs += __shfl_xor(rs, 4);
      rs += __shfl_xor(rs, 8);
      lrow[r] += rs;
    }

    // bounce P through padded LDS: D-layout -> A-layout
#pragma unroll
    for (int nf = 0; nf < 4; ++nf)
#pragma unroll
      for (int r = 0; r < 4; ++r)
        pw[(g * 4 + r) * 72 + nf * 16 + c] = f2bf(p[nf][r]);

    // O += P · V  (A = P from LDS, B = V^T tile)
#pragma unroll
    for (int ks = 0; ks < 2; ++ks) {
      bf16x8 pa = *(const bf16x8*)(pw + c * 72 + ks * 32 + g * 8);
#pragma unroll
      for (int nf = 0; nf < 4; ++nf) {
        int Rr = nf * 16 + c;
        int kblk = ks * 4 + g;
        bf16x8 vf = *(const bf16x8*)(Vtile + Rr * 64 + ((kblk ^ (Rr & 7)) * 8));
        acc[nf] = __builtin_amdgcn_mfma_f32_16x16x32_bf16(pa, vf, acc[nf], 0, 0, 0);
      }
    }
  }

  // normalize + store (bf16 scalar stores; optimize later)
  const size_t orow0 = (size_t)(b * S_ + qb * 64 + wave * 16 + g * 4);
#pragma unroll
  for (int r = 0; r < 4; ++r) {
    float inv = 1.0f / lrow[r];
#pragma unroll
    for (int nf = 0; nf < 4; ++nf)
      O[(orow0 + r) * DM + h * DK + nf * 16 + c] = f2bf(acc[nf][r] * inv);
  }
}

// ---------------- launch ----------------
extern "C" void kernel_launch(void* const* d_in, const int* in_sizes, int n_in,
                              void* d_out, int out_size, void* d_ws, size_t ws_size,
                              hipStream_t stream) {
  const float* in_q = (const float*)d_in[0];
  const float* in_k = (const float*)d_in[1];
  const float* in_v = (const float*)d_in[2];
  const float* Wq   = (const float*)d_in[3];
  const float* bq   = (const float*)d_in[4];
  const float* Wk   = (const float*)d_in[5];
  const float* bk   = (const float*)d_in[6];
  const float* Wv   = (const float*)d_in[7];
  const float* bv   = (const float*)d_in[8];
  const float* Wo   = (const float*)d_in[9];
  const float* bo   = (const float*)d_in[10];

  char* ws  = (char*)d_ws;
  u16* Qbf  = (u16*)(ws + OFF_QBF);
  u16* Kbf  = (u16*)(ws + OFF_KBF);
  u16* Vbf  = (u16*)(ws + OFF_VBF);
  u16* Vt   = (u16*)(ws + OFF_VT);
  u16* AObf = (u16*)(ws + OFF_AOBF);
  u16* WqT  = (u16*)(ws + OFF_WQT);
  u16* WoT  = (u16*)(ws + OFF_WOT);
  u16* Xqbf = (u16*)(ws + OFF_XQBF);

  cast_bf16_kernel<<<2048, 256, 0, stream>>>(in_q, Xqbf, M_ * DM / 8);
  transpose_cast_kernel<<<dim3(32, 32), dim3(32, 8), 0, stream>>>(Wq, WqT, DM, DM);
  transpose_cast_kernel<<<dim3(32, 32), dim3(32, 8), 0, stream>>>(Wo, WoT, DM, DM);
  kv_proj_kernel<<<M_ / 4, 256, 0, stream>>>(in_k, Wk, bk, Kbf);
  kv_proj_kernel<<<M_ / 4, 256, 0, stream>>>(in_v, Wv, bv, Vbf);
  transpose_v_kernel<<<dim3(2, 64, 2), dim3(32, 8), 0, stream>>>(Vbf, Vt);

  gemm_bf16_kernel<0><<<dim3(M_ / 128, DM / 128), 256, 0, stream>>>(
      Xqbf, WqT, bq, Qbf, M_, DM, DM);

  attn_kernel<<<dim3(S_ / 64, H_, B_), 256, 0, stream>>>(Qbf, Kbf, Vt, AObf);

  gemm_bf16_kernel<1><<<dim3(M_ / 128, DM / 128), 256, 0, stream>>>(
      AObf, WoT, bo, d_out, M_, DM, DM);
}

// Round 3
// 170.207 us; speedup vs baseline: 1.8932x; 1.8932x over previous
//
#include <hip/hip_runtime.h>
#include <cstdint>
#include <cstddef>

typedef unsigned short u16;
typedef __bf16 bf16x8 __attribute__((ext_vector_type(8)));
typedef float  f32x4  __attribute__((ext_vector_type(4)));
typedef float  f32x16 __attribute__((ext_vector_type(16)));
typedef unsigned u32x4 __attribute__((ext_vector_type(4)));

#define DEV __device__ __forceinline__

#define B_  2
#define S_  2048
#define DM  1024
#define H_  16
#define DK  64
#define M_  (B_ * S_)   // 4096

// ---------------- workspace layout (bytes) ----------------
// Aliasing (stream-ordered safe):
//   XVBF shares QBF   (XV read by kvproj; QBF written later by Q-GEMM)
//   XKBF shares AOBF  (XK read by kvproj; AOBF written later by attn)
constexpr size_t OFF_QBF  = 0;                                  // Q proj out bf16 [M][DM]  (also XVBF)
constexpr size_t OFF_KBF  = OFF_QBF  + (size_t)M_ * DM * 2;     // K bf16 [B][S][DK]
constexpr size_t OFF_VBF  = OFF_KBF  + (size_t)M_ * DK * 2;     // V bf16 [B][S][DK]
constexpr size_t OFF_VT   = OFF_VBF  + (size_t)M_ * DK * 2;     // V^T bf16 [B][DK][S]
constexpr size_t OFF_AOBF = OFF_VT   + (size_t)M_ * DK * 2;     // attn out bf16 [M][DM]   (also XKBF)
constexpr size_t OFF_WQT  = OFF_AOBF + (size_t)M_ * DM * 2;     // Wq^T bf16 [DM][DM]
constexpr size_t OFF_WOT  = OFF_WQT  + (size_t)DM * DM * 2;     // Wo^T bf16 [DM][DM]
constexpr size_t OFF_XQBF = OFF_WOT  + (size_t)DM * DM * 2;     // inputs_q bf16 [M][DM]
constexpr size_t OFF_WKT  = OFF_XQBF + (size_t)M_ * DM * 2;     // Wk^T bf16 [DK][DM]
constexpr size_t OFF_WVT  = OFF_WKT  + (size_t)DK * DM * 2;     // Wv^T bf16 [DK][DM]

// ---------------- helpers ----------------
DEV u16 f2bf(float f) {                 // RNE f32 -> bf16
  unsigned u = __float_as_uint(f);
  u += 0x7fffu + ((u >> 16) & 1u);
  return (u16)(u >> 16);
}

DEV unsigned cvtpk(float lo, float hi) { // pack 2 f32 -> 2 bf16 (lo in low 16)
  return (unsigned)f2bf(lo) | ((unsigned)f2bf(hi) << 16);
}

DEV void gload_lds16(const void* g, void* l) {
  __builtin_amdgcn_global_load_lds(
      (const __attribute__((address_space(1))) unsigned int*)g,
      (__attribute__((address_space(3))) unsigned int*)l, 16, 0, 0);
}

// ---------------- cast f32 -> bf16, 8 elems/thread ----------------
__global__ __launch_bounds__(256) void cast_bf16_kernel(
    const float* __restrict__ in, u16* __restrict__ out, int n8) {
  const int stride = gridDim.x * blockDim.x;
  for (int i = blockIdx.x * blockDim.x + threadIdx.x; i < n8; i += stride) {
    float4 a = ((const float4*)in)[2 * i];
    float4 b = ((const float4*)in)[2 * i + 1];
    uint4 o;
    o.x = cvtpk(a.x, a.y);
    o.y = cvtpk(a.z, a.w);
    o.z = cvtpk(b.x, b.y);
    o.w = cvtpk(b.z, b.w);
    ((uint4*)out)[i] = o;
  }
}

// ---------------- transpose + cast W[R][C] f32 -> WT[C][R] bf16 ----------------
__global__ void transpose_cast_kernel(const float* __restrict__ W,
                                      u16* __restrict__ WT, int R, int C) {
  __shared__ u16 tile[32][33];
  const int c0 = blockIdx.x * 32, r0 = blockIdx.y * 32;
  for (int i = threadIdx.y; i < 32; i += 8)
    tile[i][threadIdx.x] = f2bf(W[(size_t)(r0 + i) * C + c0 + threadIdx.x]);
  __syncthreads();
  for (int i = threadIdx.y; i < 32; i += 8)
    WT[(size_t)(c0 + i) * R + r0 + threadIdx.x] = tile[threadIdx.x][i];
}

// ---------------- transpose V bf16 [b][S][DK] -> [b][DK][S] ----------------
__global__ void transpose_v_kernel(const u16* __restrict__ V, u16* __restrict__ VT) {
  __shared__ u16 tile[32][33];
  const int b = blockIdx.z;
  const u16* Vb = V + (size_t)b * S_ * DK;
  u16* Tb = VT + (size_t)b * DK * S_;
  const int c0 = blockIdx.x * 32, r0 = blockIdx.y * 32;
  for (int i = threadIdx.y; i < 32; i += 8)
    tile[i][threadIdx.x] = Vb[(size_t)(r0 + i) * DK + c0 + threadIdx.x];
  __syncthreads();
  for (int i = threadIdx.y; i < 32; i += 8)
    Tb[(size_t)(c0 + i) * S_ + r0 + threadIdx.x] = tile[threadIdx.x][i];
}

// ---------------- K/V projection via MFMA: out[m][n] = Xbf[m][:]·WT[n][:] + b[n] ----------------
// grid (M/64, 2): y=0 -> K, y=1 -> V. block 256. BM=BN=64, BK=32.
__global__ __launch_bounds__(256) void kvproj_kernel(
    const u16* __restrict__ Xk, const u16* __restrict__ Xv,
    const u16* __restrict__ WkT, const u16* __restrict__ WvT,
    const float* __restrict__ bk, const float* __restrict__ bv,
    u16* __restrict__ Kout, u16* __restrict__ Vout) {
  __shared__ __align__(16) u16 At[64 * 32];
  __shared__ __align__(16) u16 Bt[64 * 32];
  const int sel = blockIdx.y;
  const u16* X  = sel ? Xv : Xk;
  const u16* WT = sel ? WvT : WkT;
  const float* bias = sel ? bv : bk;
  u16* out = sel ? Vout : Kout;

  const int tid = threadIdx.x, wave = tid >> 6, lane = tid & 63;
  const int g = lane >> 4, c = lane & 15;
  const int wm = wave >> 1, wn = wave & 1;
  const int bm = blockIdx.x;
  f32x4 acc[2][2] = {};

  // staging: thread = 16B slot tid; row=tid>>2, dest slot col tid&3,
  // source col pre-swizzled so read-side can use slot^(row&3)
  const int row = tid >> 2, sd = tid & 3;
  const int kc = ((sd ^ (row & 3)) * 8);
  const u16* Asrc = X  + (size_t)(bm * 64 + row) * DM + kc;
  const u16* Bsrc = WT + (size_t)row * DM + kc;

  for (int k0 = 0; k0 < DM; k0 += 32) {
    __syncthreads();
    gload_lds16(Asrc + k0, At + wave * 512);
    gload_lds16(Bsrc + k0, Bt + wave * 512);
    asm volatile("s_waitcnt vmcnt(0)" ::: "memory");
    __syncthreads();

    bf16x8 af[2], bfr[2];
#pragma unroll
    for (int mf = 0; mf < 2; ++mf) {
      const int ra = wm * 32 + mf * 16 + c;
      af[mf] = *(const bf16x8*)(At + ra * 32 + ((g ^ (ra & 3)) * 8));
    }
#pragma unroll
    for (int nf = 0; nf < 2; ++nf) {
      const int rb = wn * 32 + nf * 16 + c;
      bfr[nf] = *(const bf16x8*)(Bt + rb * 32 + ((g ^ (rb & 3)) * 8));
    }
#pragma unroll
    for (int mf = 0; mf < 2; ++mf)
#pragma unroll
      for (int nf = 0; nf < 2; ++nf)
        acc[mf][nf] = __builtin_amdgcn_mfma_f32_16x16x32_bf16(
            af[mf], bfr[nf], acc[mf][nf], 0, 0, 0);
  }

#pragma unroll
  for (int nf = 0; nf < 2; ++nf) {
    const int col = wn * 32 + nf * 16 + c;
    const float bs = bias[col];
#pragma unroll
    for (int mf = 0; mf < 2; ++mf)
#pragma unroll
      for (int r = 0; r < 4; ++r)
        out[(size_t)(bm * 64 + wm * 32 + mf * 16 + g * 4 + r) * DK + col] =
            f2bf(acc[mf][nf][r] + bs);
  }
}

// ---------------- m97-style 128x128 bf16 GEMM: C = (A*BT^T + bias) * oscale ----------------
template <int OUT_F32>
__global__ __launch_bounds__(256) void gemm_bf16_kernel(
    const u16* __restrict__ A, const u16* __restrict__ BT,
    const float* __restrict__ bias, void* __restrict__ Cout,
    int M, int N, int K, float oscale) {
  __shared__ __align__(16) u16 At[128 * 32];
  __shared__ __align__(16) u16 Bt[128 * 32];
  const int tid = threadIdx.x, wave = tid >> 6, lane = tid & 63;
  const int bm = blockIdx.x, bn = blockIdx.y;
  const int wm = wave >> 1, wn = wave & 1;
  const int g = lane >> 4, c = lane & 15;
  f32x4 acc[4][4] = {};

  for (int k0 = 0; k0 < K; k0 += 32) {
    __syncthreads();
#pragma unroll
    for (int j = 0; j < 2; ++j) {
      int ls = (j * 4 + wave) * 64 + lane;
      int row = ls >> 2, kc = (ls & 3) * 8;
      gload_lds16(A  + (size_t)(bm * 128 + row) * K + k0 + kc,
                  (char*)At + (size_t)(j * 4 + wave) * 1024);
      gload_lds16(BT + (size_t)(bn * 128 + row) * K + k0 + kc,
                  (char*)Bt + (size_t)(j * 4 + wave) * 1024);
    }
    asm volatile("s_waitcnt vmcnt(0)" ::: "memory");
    __syncthreads();

    bf16x8 af[4], bfr[4];
#pragma unroll
    for (int mf = 0; mf < 4; ++mf)
      af[mf] = *(const bf16x8*)(At + (wm * 64 + mf * 16 + c) * 32 + g * 8);
#pragma unroll
    for (int nf = 0; nf < 4; ++nf)
      bfr[nf] = *(const bf16x8*)(Bt + (wn * 64 + nf * 16 + c) * 32 + g * 8);
#pragma unroll
    for (int mf = 0; mf < 4; ++mf)
#pragma unroll
      for (int nf = 0; nf < 4; ++nf)
        acc[mf][nf] = __builtin_amdgcn_mfma_f32_16x16x32_bf16(
            af[mf], bfr[nf], acc[mf][nf], 0, 0, 0);
  }

  const int colb = bn * 128 + wn * 64 + c;
  const int rowb = bm * 128 + wm * 64 + g * 4;
#pragma unroll
  for (int nf = 0; nf < 4; ++nf) {
    float bs = bias[colb + nf * 16];
#pragma unroll
    for (int mf = 0; mf < 4; ++mf) {
#pragma unroll
      for (int r = 0; r < 4; ++r) {
        size_t idx = (size_t)(rowb + mf * 16 + r) * N + colb + nf * 16;
        float v = (acc[mf][nf][r] + bs) * oscale;
        if (OUT_F32) ((float*)Cout)[idx] = v;
        else         ((u16*)Cout)[idx]   = f2bf(v);
      }
    }
  }
}

// ---------------- causal MQA flash attention, swapped-QK 32x32 structure ----------------
// grid (S/64, H, B); block 128 = 2 waves, each wave owns 32 q rows (q = lane&31).
// Q is PRE-SCALED by 1/8. K LDS [kv][64], Vt LDS [dv][kv], 16B-slot XOR swizzle,
// double-buffered, 1 barrier/stage, counted overlap via post-barrier prefetch.
__global__ __launch_bounds__(128) void attn_kernel(
    const u16* __restrict__ Q,   // [B*S][DM] bf16 (head h at col h*64), pre-scaled
    const u16* __restrict__ K,   // [B][S][DK] bf16
    const u16* __restrict__ Vt,  // [B][DK][S] bf16
    u16* __restrict__ O) {       // [B*S][DM] bf16
  __shared__ __align__(16) u16 Ktile[2][64 * 64];
  __shared__ __align__(16) u16 Vtile[2][64 * 64];

  const int qb = blockIdx.x, h = blockIdx.y, b = blockIdx.z;
  const int wave = threadIdx.x >> 6, lane = threadIdx.x & 63;
  const int q31 = lane & 31, hi = lane >> 5;
  const int qrow = qb * 64 + wave * 32 + q31;
  const int nt = qb + 1;

  // Q B-fragments: B row = q = lane&31, k = hi*8 + i within each 16-chunk
  const u16* Qp = Q + (size_t)(b * S_ + qrow) * DM + h * DK;
  bf16x8 qf[4];
#pragma unroll
  for (int ks = 0; ks < 4; ++ks)
    qf[ks] = *(const bf16x8*)(Qp + ks * 16 + hi * 8);

  f32x16 acc0 = {}, acc1 = {};
  float m_ = -1e30f, l_ = 0.f;

  // staging: 8 chunks of 8 rows x 128B each; wave0 stages K, wave1 stages Vt
  const int srow = lane >> 3;
  const int sslot = (lane & 7) ^ (lane >> 3);
  const u16* kb = K  + (size_t)b * S_ * DK + (size_t)srow * DK + sslot * 8;
  const u16* vb = Vt + (size_t)b * DK * S_ + (size_t)srow * S_ + sslot * 8;

  // prologue: stage t=0 into buf 0
  if (wave == 0) {
#pragma unroll
    for (int j = 0; j < 8; ++j) gload_lds16(kb + j * 512, &Ktile[0][j * 512]);
  } else {
#pragma unroll
    for (int j = 0; j < 8; ++j) gload_lds16(vb + (size_t)j * 8 * S_, &Vtile[0][j * 512]);
  }

  const int rsw = q31 & 7;

  for (int t = 0; t < nt; ++t) {
    const int bsel = t & 1;
    asm volatile("s_waitcnt vmcnt(0)" ::: "memory");
    __syncthreads();
    if (t + 1 < nt) {           // prefetch next tile into other buffer
      const int nb = bsel ^ 1;
      if (wave == 0) {
#pragma unroll
        for (int j = 0; j < 8; ++j)
          gload_lds16(kb + (size_t)(t + 1) * 4096 + j * 512, &Ktile[nb][j * 512]);
      } else {
#pragma unroll
        for (int j = 0; j < 8; ++j)
          gload_lds16(vb + (t + 1) * 64 + (size_t)j * 8 * S_, &Vtile[nb][j * 512]);
      }
    }
    const u16* Kl = Ktile[bsel];
    const u16* Vl = Vtile[bsel];
    const int kv0 = t * 64;
    const bool diag = (t == nt - 1);
    const bool skipHi = diag && (wave == 0);   // kv 32..63 fully masked for wave0's diag

    // S^T = K · Q^T : D[kv][q], q = lane&31, kv = at*32 + crow(r,hi)
    f32x16 sf0 = {}, sf1 = {};
    __builtin_amdgcn_s_setprio(1);
#pragma unroll
    for (int ks = 0; ks < 4; ++ks) {
      const int sl = ((ks * 2 + hi) ^ rsw) * 8;
      bf16x8 kf0 = *(const bf16x8*)(Kl + q31 * 64 + sl);
      sf0 = __builtin_amdgcn_mfma_f32_32x32x16_bf16(kf0, qf[ks], sf0, 0, 0, 0);
      if (!skipHi) {
        bf16x8 kf1 = *(const bf16x8*)(Kl + (32 + q31) * 64 + sl);
        sf1 = __builtin_amdgcn_mfma_f32_32x32x16_bf16(kf1, qf[ks], sf1, 0, 0, 0);
      }
    }
    __builtin_amdgcn_s_setprio(0);

    // causal mask (diag tile only)
    if (diag) {
#pragma unroll
      for (int r = 0; r < 16; ++r) {
        const int kvl = (r & 3) + 8 * (r >> 2) + 4 * hi;
        if (kv0 + kvl > qrow)      sf0[r] = -1e30f;
        if (kv0 + 32 + kvl > qrow) sf1[r] = -1e30f;
      }
    }

    // per-row max (lane-local; combine the two kv-halves across lane^32)
    float pm = -1e30f;
#pragma unroll
    for (int r = 0; r < 16; ++r) pm = fmaxf(pm, fmaxf(sf0[r], sf1[r]));
    pm = fmaxf(pm, __shfl_xor(pm, 32));

    // defer-max (T13): rescale only when max grew past threshold
    if (__any(pm > m_ + 8.f)) {
      const float nm = fmaxf(m_, pm);
      const float cr = __expf(m_ - nm);
      m_ = nm; l_ *= cr;
      if (t > 0) {
#pragma unroll
        for (int r = 0; r < 16; ++r) {
          const int rr = (r & 3) + 8 * (r >> 2) + 4 * hi;
          const float crr = __shfl(cr, (hi << 5) | rr);
          acc0[r] *= crr; acc1[r] *= crr;
        }
      }
    }

    // P = exp(S - m), row-sum
    float rs = 0.f;
#pragma unroll
    for (int r = 0; r < 16; ++r) { float e = __expf(sf0[r] - m_); sf0[r] = e; rs += e; }
    if (!skipHi) {
#pragma unroll
      for (int r = 0; r < 16; ++r) { float e = __expf(sf1[r] - m_); sf1[r] = e; rs += e; }
    }
    rs += __shfl_xor(rs, 32);
    l_ += rs;

    // O += P · V : pa = P as A-operand (cvt_pk + cross-half exchange), B = Vt rows
    __builtin_amdgcn_s_setprio(1);
#pragma unroll
    for (int at = 0; at < 2; ++at) {
      if (at == 1 && skipHi) break;
      const f32x16& sfv = at ? sf1 : sf0;
#pragma unroll
      for (int half = 0; half < 2; ++half) {
        const int rb = half * 8;
        unsigned w0 = cvtpk(sfv[rb + 0], sfv[rb + 1]);
        unsigned w1 = cvtpk(sfv[rb + 2], sfv[rb + 3]);
        unsigned w2 = cvtpk(sfv[rb + 4], sfv[rb + 5]);
        unsigned w3 = cvtpk(sfv[rb + 6], sfv[rb + 7]);
        const unsigned x0 = __shfl_xor(w0, 32), x1 = __shfl_xor(w1, 32);
        const unsigned x2 = __shfl_xor(w2, 32), x3 = __shfl_xor(w3, 32);
        u32x4 pw;
        pw[0] = hi ? x2 : w0;    // kvloc (hi*8+0, +1)
        pw[1] = hi ? x3 : w1;    // kvloc (hi*8+2, +3)
        pw[2] = hi ? w2 : x0;    // kvloc (hi*8+4, +5)
        pw[3] = hi ? w3 : x1;    // kvloc (hi*8+6, +7)
        const bf16x8 pa = __builtin_bit_cast(bf16x8, pw);
        const int ksg = at * 2 + half;
        const int sl = ((ksg * 2 + hi) ^ rsw) * 8;
        const bf16x8 vf0 = *(const bf16x8*)(Vl + q31 * 64 + sl);
        const bf16x8 vf1 = *(const bf16x8*)(Vl + (32 + q31) * 64 + sl);
        acc0 = __builtin_amdgcn_mfma_f32_32x32x16_bf16(pa, vf0, acc0, 0, 0, 0);
        acc1 = __builtin_amdgcn_mfma_f32_32x32x16_bf16(pa, vf1, acc1, 0, 0, 0);
      }
    }
    __builtin_amdgcn_s_setprio(0);
  }

  // epilogue: normalize + store. acc row q' = crow(r,hi), col dv = vt*32 + q31
  const float linv = 1.f / l_;
  u16* Op = O + (size_t)(b * S_ + qb * 64 + wave * 32) * DM + h * DK;
#pragma unroll
  for (int r = 0; r < 16; ++r) {
    const int rr = (r & 3) + 8 * (r >> 2) + 4 * hi;
    const float lr = __shfl(linv, (hi << 5) | rr);
    Op[(size_t)rr * DM + q31]      = f2bf(acc0[r] * lr);
    Op[(size_t)rr * DM + 32 + q31] = f2bf(acc1[r] * lr);
  }
}

// ---------------- launch ----------------
extern "C" void kernel_launch(void* const* d_in, const int* in_sizes, int n_in,
                              void* d_out, int out_size, void* d_ws, size_t ws_size,
                              hipStream_t stream) {
  const float* in_q = (const float*)d_in[0];
  const float* in_k = (const float*)d_in[1];
  const float* in_v = (const float*)d_in[2];
  const float* Wq   = (const float*)d_in[3];
  const float* bq   = (const float*)d_in[4];
  const float* Wk   = (const float*)d_in[5];
  const float* bk   = (const float*)d_in[6];
  const float* Wv   = (const float*)d_in[7];
  const float* bv   = (const float*)d_in[8];
  const float* Wo   = (const float*)d_in[9];
  const float* bo   = (const float*)d_in[10];

  char* ws  = (char*)d_ws;
  u16* Qbf  = (u16*)(ws + OFF_QBF);
  u16* Kbf  = (u16*)(ws + OFF_KBF);
  u16* Vbf  = (u16*)(ws + OFF_VBF);
  u16* Vt   = (u16*)(ws + OFF_VT);
  u16* AObf = (u16*)(ws + OFF_AOBF);
  u16* WqT  = (u16*)(ws + OFF_WQT);
  u16* WoT  = (u16*)(ws + OFF_WOT);
  u16* Xqbf = (u16*)(ws + OFF_XQBF);
  u16* WkT  = (u16*)(ws + OFF_WKT);
  u16* WvT  = (u16*)(ws + OFF_WVT);
  u16* Xkbf = AObf;   // alias: dead before attn writes AObf
  u16* Xvbf = Qbf;    // alias: dead before Q-GEMM writes Qbf

  cast_bf16_kernel<<<2048, 256, 0, stream>>>(in_q, Xqbf, M_ * DM / 8);
  cast_bf16_kernel<<<2048, 256, 0, stream>>>(in_k, Xkbf, M_ * DM / 8);
  cast_bf16_kernel<<<2048, 256, 0, stream>>>(in_v, Xvbf, M_ * DM / 8);

  transpose_cast_kernel<<<dim3(32, 32), dim3(32, 8), 0, stream>>>(Wq, WqT, DM, DM);
  transpose_cast_kernel<<<dim3(32, 32), dim3(32, 8), 0, stream>>>(Wo, WoT, DM, DM);
  transpose_cast_kernel<<<dim3(2, 32),  dim3(32, 8), 0, stream>>>(Wk, WkT, DM, DK);
  transpose_cast_kernel<<<dim3(2, 32),  dim3(32, 8), 0, stream>>>(Wv, WvT, DM, DK);

  kvproj_kernel<<<dim3(M_ / 64, 2), 256, 0, stream>>>(
      Xkbf, Xvbf, WkT, WvT, bk, bv, Kbf, Vbf);

  transpose_v_kernel<<<dim3(2, 64, 2), dim3(32, 8), 0, stream>>>(Vbf, Vt);

  // Q projection, pre-scaled by 1/sqrt(dk)=1/8 (exact in bf16)
  gemm_bf16_kernel<0><<<dim3(M_ / 128, DM / 128), 256, 0, stream>>>(
      Xqbf, WqT, bq, Qbf, M_, DM, DM, 0.125f);

  attn_kernel<<<dim3(S_ / 64, H_, B_), 128, 0, stream>>>(Qbf, Kbf, Vt, AObf);

  gemm_bf16_kernel<1><<<dim3(M_ / 128, DM / 128), 256, 0, stream>>>(
      AObf, WoT, bo, d_out, M_, DM, DM, 1.0f);
}